// Round 1
// baseline (638.987 us; speedup 1.0000x reference)
//
#include <hip/hip_runtime.h>
#include <math.h>

#define H 8
#define C 32
#define HC 256      // H*C
#define FE 16
#define FIN 128
#define NEG_SLOPE 0.2f

// ---------------- M[f][h] = sum_c W_edge[(h*C+c)*FE+f] * att_edge[h*C+c] ----------------
__global__ void k_M(const float* __restrict__ W_edge, const float* __restrict__ att_edge,
                    float* __restrict__ M) {
  int t = threadIdx.x;          // 128 threads: f = t>>3, h = t&7
  int f = t >> 3, h = t & 7;
  float acc = 0.f;
#pragma unroll
  for (int c = 0; c < C; ++c)
    acc += W_edge[(h * C + c) * FE + f] * att_edge[h * C + c];
  M[f * H + h] = acc;
}

// ---------------- xh = x @ W.T   (M=N rows, K=128, Ncols=256), 64x64 tiles ----------------
__global__ __launch_bounds__(256) void k_xh(const float* __restrict__ x,
                                            const float* __restrict__ W,
                                            float* __restrict__ xh, int N) {
  __shared__ float As[16][65];
  __shared__ float Bs[16][65];
  int t = threadIdx.x;
  int tx = t & 15, ty = t >> 4;
  int rb = blockIdx.x * 64;
  int cb = blockIdx.y * 64;
  float acc[4][4] = {};
  for (int k0 = 0; k0 < FIN; k0 += 16) {
    int idx = t * 4;
    int row = idx >> 4, kk = idx & 15;
    float4 va = make_float4(0.f, 0.f, 0.f, 0.f);
    if (rb + row < N) va = *(const float4*)&x[(size_t)(rb + row) * FIN + k0 + kk];
    As[kk + 0][row] = va.x; As[kk + 1][row] = va.y; As[kk + 2][row] = va.z; As[kk + 3][row] = va.w;
    float4 vb = *(const float4*)&W[(size_t)(cb + row) * FIN + k0 + kk];
    Bs[kk + 0][row] = vb.x; Bs[kk + 1][row] = vb.y; Bs[kk + 2][row] = vb.z; Bs[kk + 3][row] = vb.w;
    __syncthreads();
#pragma unroll
    for (int k = 0; k < 16; ++k) {
      float a[4], b[4];
#pragma unroll
      for (int i = 0; i < 4; ++i) a[i] = As[k][ty * 4 + i];
#pragma unroll
      for (int j = 0; j < 4; ++j) b[j] = Bs[k][tx * 4 + j];
#pragma unroll
      for (int i = 0; i < 4; ++i)
#pragma unroll
        for (int j = 0; j < 4; ++j) acc[i][j] = fmaf(a[i], b[j], acc[i][j]);
    }
    __syncthreads();
  }
#pragma unroll
  for (int i = 0; i < 4; ++i) {
    int r = rb + ty * 4 + i;
    if (r < N) {
#pragma unroll
      for (int j = 0; j < 4; ++j) xh[(size_t)r * HC + cb + tx * 4 + j] = acc[i][j];
    }
  }
}

// ---------------- a_src[n,h], a_dst[n,h] ----------------
__global__ __launch_bounds__(256) void k_att(const float* __restrict__ xh,
                                             const float* __restrict__ att_src,
                                             const float* __restrict__ att_dst,
                                             float* __restrict__ a_src,
                                             float* __restrict__ a_dst, int N) {
  int n = blockIdx.x;
  int t = threadIdx.x;
  float v = xh[(size_t)n * HC + t];
  float as = v * att_src[t];
  float ad = v * att_dst[t];
#pragma unroll
  for (int off = 16; off > 0; off >>= 1) {
    as += __shfl_down(as, off, 32);
    ad += __shfl_down(ad, off, 32);
  }
  if ((t & 31) == 0) {
    a_src[n * H + (t >> 5)] = as;
    a_dst[n * H + (t >> 5)] = ad;
  }
}

// ---------------- per-edge: deg histogram + a_edge = ea @ M ----------------
__global__ __launch_bounds__(256) void k_edge(const int* __restrict__ ei,
                                              const float* __restrict__ ea,
                                              const float* __restrict__ M,
                                              float* __restrict__ a_edge,
                                              int* __restrict__ deg, int E) {
  __shared__ float Ms[FE * H];
  int t = threadIdx.x;
  if (t < FE * H) Ms[t] = M[t];
  __syncthreads();
  int e = blockIdx.x * 256 + t;
  if (e >= E) return;
  int d = ei[E + e];
  atomicAdd(&deg[d], 1);
  const float4* p = (const float4*)&ea[(size_t)e * FE];
  float4 v0 = p[0], v1 = p[1], v2 = p[2], v3 = p[3];
  float eav[FE] = {v0.x, v0.y, v0.z, v0.w, v1.x, v1.y, v1.z, v1.w,
                   v2.x, v2.y, v2.z, v2.w, v3.x, v3.y, v3.z, v3.w};
  float o[H];
#pragma unroll
  for (int h = 0; h < H; ++h) {
    float acc = 0.f;
#pragma unroll
    for (int f = 0; f < FE; ++f) acc += eav[f] * Ms[f * H + h];
    o[h] = acc;
  }
  float4* q = (float4*)&a_edge[(size_t)e * H];
  q[0] = make_float4(o[0], o[1], o[2], o[3]);
  q[1] = make_float4(o[4], o[5], o[6], o[7]);
}

// ---------------- single-block exclusive scan over deg → rowptr, wo ----------------
__global__ __launch_bounds__(1024) void k_scan(const int* __restrict__ deg,
                                               int* __restrict__ rowptr,
                                               int* __restrict__ wo, int N) {
  __shared__ int buf[1024];
  __shared__ int carry;
  int t = threadIdx.x;
  if (t == 0) carry = 0;
  __syncthreads();
  for (int base = 0; base < N; base += 1024) {
    int i = base + t;
    int v = (i < N) ? deg[i] : 0;
    buf[t] = v;
    __syncthreads();
    for (int off = 1; off < 1024; off <<= 1) {
      int y = (t >= off) ? buf[t - off] : 0;
      __syncthreads();
      buf[t] += y;
      __syncthreads();
    }
    int incl = buf[t];
    int excl = incl - v;
    if (i < N) { rowptr[i] = carry + excl; wo[i] = carry + excl; }
    int total = buf[1023];
    __syncthreads();
    if (t == 0) carry += total;
    __syncthreads();
  }
  if (t == 0) rowptr[N] = carry;
}

// ---------------- scatter edges into CSR ----------------
__global__ __launch_bounds__(256) void k_scatter(const int* __restrict__ ei,
                                                 int* __restrict__ wo,
                                                 int2* __restrict__ col, int E) {
  int e = blockIdx.x * 256 + threadIdx.x;
  if (e >= E) return;
  int s = ei[e], d = ei[E + e];
  int pos = atomicAdd(&wo[d], 1);
  col[pos] = make_int2(s, e);
}

// ---------------- node-centric softmax + message aggregation ----------------
__global__ __launch_bounds__(256) void k_node(const float* __restrict__ xh,
                                              const float* __restrict__ a_src,
                                              const float* __restrict__ a_dst,
                                              float* __restrict__ ae,   // a_edge → alpha → ex (in place)
                                              const int* __restrict__ rowptr,
                                              const int2* __restrict__ col,
                                              const float* __restrict__ bias,
                                              float* __restrict__ out, int N) {
  int n = blockIdx.x;
  int t = threadIdx.x;
  int start = rowptr[n], end = rowptr[n + 1];
  int deg = end - start;
  __shared__ float r1[256], r2[256];
  __shared__ float sh_asrc[H], sh_adst[H];
  __shared__ float amax_s[H], aself_s[H], wself_s[H], inv_s[H];
  if (t < H) { sh_asrc[t] = a_src[n * H + t]; sh_adst[t] = a_dst[n * H + t]; }
  __syncthreads();
  int h8 = t & 7;

  // pass 1: alpha = leaky(a_src[src]+a_dst[n]+a_edge); track per-head max and raw a_edge sum
  float pmax = -1e30f, psum = 0.f;
  for (int k = t; k < deg * H; k += 256) {
    int2 se = col[start + (k >> 3)];
    float aev = ae[(size_t)se.y * H + h8];
    psum += aev;
    float al = a_src[se.x * H + h8] + sh_adst[h8] + aev;
    al = (al >= 0.f) ? al : NEG_SLOPE * al;
    ae[(size_t)se.y * H + h8] = al;
    pmax = fmaxf(pmax, al);
  }
  r1[t] = pmax; r2[t] = psum;
  __syncthreads();
  for (int off = 128; off >= 8; off >>= 1) {
    if (t < off) { r1[t] = fmaxf(r1[t], r1[t + off]); r2[t] += r2[t + off]; }
    __syncthreads();
  }
  if (t < H) {
    float aself = sh_asrc[t] + sh_adst[t] + r2[t] / fmaxf((float)deg, 1.f);
    aself = (aself >= 0.f) ? aself : NEG_SLOPE * aself;
    aself_s[t] = aself;
    amax_s[t] = fmaxf(r1[t], aself);
  }
  __syncthreads();

  // pass 2: ex = exp(alpha - amax); per-head denom
  float pden = 0.f;
  for (int k = t; k < deg * H; k += 256) {
    int2 se = col[start + (k >> 3)];
    float al = ae[(size_t)se.y * H + h8];
    float ex = __expf(al - amax_s[h8]);
    ae[(size_t)se.y * H + h8] = ex;
    pden += ex;
  }
  r1[t] = pden;
  __syncthreads();
  for (int off = 128; off >= 8; off >>= 1) {
    if (t < off) r1[t] += r1[t + off];
    __syncthreads();
  }
  if (t < H) {
    float exs = __expf(aself_s[t] - amax_s[t]);
    float inv = 1.f / (r1[t] + exs);
    inv_s[t] = inv;
    wself_s[t] = exs * inv;
  }
  __syncthreads();

  // pass 3: out[n,h,c] = sum_e ex*inv * xh[src] + self term; then head-mean
  int h = t >> 5;
  float invh = inv_s[h];
  float acc = xh[(size_t)n * HC + t] * wself_s[h];
  for (int j = 0; j < deg; ++j) {
    int2 se = col[start + j];
    float w = ae[(size_t)se.y * H + h] * invh;
    acc = fmaf(xh[(size_t)se.x * HC + t], w, acc);
  }
  r1[t] = acc;
  __syncthreads();
  if (t < C) {
    float s = 0.f;
#pragma unroll
    for (int hh = 0; hh < H; ++hh) s += r1[hh * C + t];
    out[(size_t)n * C + t] = s * 0.125f + bias[t];
  }
}

extern "C" void kernel_launch(void* const* d_in, const int* in_sizes, int n_in,
                              void* d_out, int out_size, void* d_ws, size_t ws_size,
                              hipStream_t stream) {
  const float* x        = (const float*)d_in[0];
  const int*   ei       = (const int*)d_in[1];
  const float* ea       = (const float*)d_in[2];
  const float* W        = (const float*)d_in[3];
  const float* W_edge   = (const float*)d_in[4];
  const float* att_src  = (const float*)d_in[5];
  const float* att_dst  = (const float*)d_in[6];
  const float* att_edge = (const float*)d_in[7];
  const float* bias     = (const float*)d_in[8];
  float* out = (float*)d_out;

  int N = in_sizes[0] / FIN;
  int E = in_sizes[1] / 2;

  // workspace carve-up (256B aligned)
  char* ws = (char*)d_ws;
  auto take = [&](size_t bytes) {
    char* p = ws;
    ws += (bytes + 255) & ~(size_t)255;
    return p;
  };
  float* xh     = (float*)take((size_t)N * HC * 4);
  float* a_src  = (float*)take((size_t)N * H * 4);
  float* a_dst  = (float*)take((size_t)N * H * 4);
  float* a_edge = (float*)take((size_t)E * H * 4);
  float* Mbuf   = (float*)take(FE * H * 4);
  int*   deg    = (int*)take((size_t)N * 4);
  int*   rowptr = (int*)take((size_t)(N + 1) * 4);
  int*   wo     = (int*)take((size_t)N * 4);
  int2*  col    = (int2*)take((size_t)E * 8);

  hipMemsetAsync(deg, 0, (size_t)N * 4, stream);
  k_M<<<1, 128, 0, stream>>>(W_edge, att_edge, Mbuf);
  k_xh<<<dim3((N + 63) / 64, HC / 64), 256, 0, stream>>>(x, W, xh, N);
  k_att<<<N, 256, 0, stream>>>(xh, att_src, att_dst, a_src, a_dst, N);
  k_edge<<<(E + 255) / 256, 256, 0, stream>>>(ei, ea, Mbuf, a_edge, deg, E);
  k_scan<<<1, 1024, 0, stream>>>(deg, rowptr, wo, N);
  k_scatter<<<(E + 255) / 256, 256, 0, stream>>>(ei, wo, col, E);
  k_node<<<N, 256, 0, stream>>>(xh, a_src, a_dst, a_edge, rowptr, col, bias, out, N);
}

// Round 2
// 436.679 us; speedup vs baseline: 1.4633x; 1.4633x over previous
//
#include <hip/hip_runtime.h>
#include <math.h>

#define H 8
#define C 32
#define HC 256      // H*C
#define FE 16
#define FIN 128
#define NEG_SLOPE 0.2f

// ---------------- M[f][h] = sum_c W_edge[(h*C+c)*FE+f] * att_edge[h*C+c] ----------------
__global__ void k_M(const float* __restrict__ W_edge, const float* __restrict__ att_edge,
                    float* __restrict__ M) {
  int t = threadIdx.x;          // 128 threads: f = t>>3, h = t&7
  int f = t >> 3, h = t & 7;
  float acc = 0.f;
#pragma unroll
  for (int c = 0; c < C; ++c)
    acc += W_edge[(h * C + c) * FE + f] * att_edge[h * C + c];
  M[f * H + h] = acc;
}

// ---------------- xh = x @ W.T   (M=N rows, K=128, Ncols=256), 64x64 tiles ----------------
__global__ __launch_bounds__(256) void k_xh(const float* __restrict__ x,
                                            const float* __restrict__ W,
                                            float* __restrict__ xh, int N) {
  __shared__ float As[16][65];
  __shared__ float Bs[16][65];
  int t = threadIdx.x;
  int tx = t & 15, ty = t >> 4;
  int rb = blockIdx.x * 64;
  int cb = blockIdx.y * 64;
  float acc[4][4] = {};
  for (int k0 = 0; k0 < FIN; k0 += 16) {
    int idx = t * 4;
    int row = idx >> 4, kk = idx & 15;
    float4 va = make_float4(0.f, 0.f, 0.f, 0.f);
    if (rb + row < N) va = *(const float4*)&x[(size_t)(rb + row) * FIN + k0 + kk];
    As[kk + 0][row] = va.x; As[kk + 1][row] = va.y; As[kk + 2][row] = va.z; As[kk + 3][row] = va.w;
    float4 vb = *(const float4*)&W[(size_t)(cb + row) * FIN + k0 + kk];
    Bs[kk + 0][row] = vb.x; Bs[kk + 1][row] = vb.y; Bs[kk + 2][row] = vb.z; Bs[kk + 3][row] = vb.w;
    __syncthreads();
#pragma unroll
    for (int k = 0; k < 16; ++k) {
      float a[4], b[4];
#pragma unroll
      for (int i = 0; i < 4; ++i) a[i] = As[k][ty * 4 + i];
#pragma unroll
      for (int j = 0; j < 4; ++j) b[j] = Bs[k][tx * 4 + j];
#pragma unroll
      for (int i = 0; i < 4; ++i)
#pragma unroll
        for (int j = 0; j < 4; ++j) acc[i][j] = fmaf(a[i], b[j], acc[i][j]);
    }
    __syncthreads();
  }
#pragma unroll
  for (int i = 0; i < 4; ++i) {
    int r = rb + ty * 4 + i;
    if (r < N) {
#pragma unroll
      for (int j = 0; j < 4; ++j) xh[(size_t)r * HC + cb + tx * 4 + j] = acc[i][j];
    }
  }
}

// ---------------- a_src[n,h], a_dst[n,h] ----------------
__global__ __launch_bounds__(256) void k_att(const float* __restrict__ xh,
                                             const float* __restrict__ att_src,
                                             const float* __restrict__ att_dst,
                                             float* __restrict__ a_src,
                                             float* __restrict__ a_dst, int N) {
  int n = blockIdx.x;
  int t = threadIdx.x;
  float v = xh[(size_t)n * HC + t];
  float as = v * att_src[t];
  float ad = v * att_dst[t];
#pragma unroll
  for (int off = 16; off > 0; off >>= 1) {
    as += __shfl_down(as, off, 32);
    ad += __shfl_down(ad, off, 32);
  }
  if ((t & 31) == 0) {
    a_src[n * H + (t >> 5)] = as;
    a_dst[n * H + (t >> 5)] = ad;
  }
}

// ---------------- per-edge: deg histogram + a_edge = ea @ M ----------------
__global__ __launch_bounds__(256) void k_edge(const int* __restrict__ ei,
                                              const float* __restrict__ ea,
                                              const float* __restrict__ M,
                                              float* __restrict__ a_edge,
                                              int* __restrict__ deg, int E) {
  __shared__ float Ms[FE * H];
  int t = threadIdx.x;
  if (t < FE * H) Ms[t] = M[t];
  __syncthreads();
  int e = blockIdx.x * 256 + t;
  if (e >= E) return;
  int d = ei[E + e];
  atomicAdd(&deg[d], 1);
  const float4* p = (const float4*)&ea[(size_t)e * FE];
  float4 v0 = p[0], v1 = p[1], v2 = p[2], v3 = p[3];
  float eav[FE] = {v0.x, v0.y, v0.z, v0.w, v1.x, v1.y, v1.z, v1.w,
                   v2.x, v2.y, v2.z, v2.w, v3.x, v3.y, v3.z, v3.w};
  float o[H];
#pragma unroll
  for (int h = 0; h < H; ++h) {
    float acc = 0.f;
#pragma unroll
    for (int f = 0; f < FE; ++f) acc += eav[f] * Ms[f * H + h];
    o[h] = acc;
  }
  float4* q = (float4*)&a_edge[(size_t)e * H];
  q[0] = make_float4(o[0], o[1], o[2], o[3]);
  q[1] = make_float4(o[4], o[5], o[6], o[7]);
}

// ---------------- hierarchical scan: block sums ----------------
__global__ __launch_bounds__(256) void k_scan1(const int* __restrict__ deg,
                                               int* __restrict__ bsum, int N) {
  int t = threadIdx.x;
  int i = blockIdx.x * 256 + t;
  int v = (i < N) ? deg[i] : 0;
#pragma unroll
  for (int m = 1; m < 64; m <<= 1) v += __shfl_xor(v, m, 64);
  __shared__ int wsum[4];
  if ((t & 63) == 0) wsum[t >> 6] = v;
  __syncthreads();
  if (t == 0) bsum[blockIdx.x] = wsum[0] + wsum[1] + wsum[2] + wsum[3];
}

// ---------------- scan of block sums (single small block) ----------------
__global__ __launch_bounds__(256) void k_scan2(const int* __restrict__ bsum,
                                               int* __restrict__ boff, int nb) {
  __shared__ int buf[256];
  int t = threadIdx.x;
  int v = (t < nb) ? bsum[t] : 0;
  buf[t] = v;
  __syncthreads();
  for (int off = 1; off < 256; off <<= 1) {
    int y = (t >= off) ? buf[t - off] : 0;
    __syncthreads();
    buf[t] += y;
    __syncthreads();
  }
  if (t < nb) boff[t] = buf[t] - v;   // exclusive
}

// ---------------- final: per-block scan + offset → rowptr, wo ----------------
__global__ __launch_bounds__(256) void k_scan3(const int* __restrict__ deg,
                                               const int* __restrict__ boff,
                                               int* __restrict__ rowptr,
                                               int* __restrict__ wo, int N, int E) {
  __shared__ int buf[256];
  int t = threadIdx.x;
  int i = blockIdx.x * 256 + t;
  int v = (i < N) ? deg[i] : 0;
  buf[t] = v;
  __syncthreads();
  for (int off = 1; off < 256; off <<= 1) {
    int y = (t >= off) ? buf[t - off] : 0;
    __syncthreads();
    buf[t] += y;
    __syncthreads();
  }
  if (i < N) {
    int ex = boff[blockIdx.x] + buf[t] - v;
    rowptr[i] = ex;
    wo[i] = ex;
  }
  if (i == 0) rowptr[N] = E;
}

// ---------------- scatter edges into CSR; copy a_edge into CSR order ----------------
__global__ __launch_bounds__(256) void k_scatter(const int* __restrict__ ei,
                                                 const float* __restrict__ a_edge,
                                                 int* __restrict__ wo,
                                                 int* __restrict__ colsrc,
                                                 float* __restrict__ apre, int E) {
  int e = blockIdx.x * 256 + threadIdx.x;
  if (e >= E) return;
  int s = ei[e], d = ei[E + e];
  int pos = atomicAdd(&wo[d], 1);
  colsrc[pos] = s;
  const float4* p = (const float4*)&a_edge[(size_t)e * H];
  float4* q = (float4*)&apre[(size_t)pos * H];
  q[0] = p[0];
  q[1] = p[1];
}

// ---------------- wave-per-node softmax + aggregation (no barriers) ----------------
__global__ __launch_bounds__(256) void k_node(const float* __restrict__ xh,
                                              const float* __restrict__ a_src,
                                              const float* __restrict__ a_dst,
                                              float* __restrict__ apre,   // raw ae (CSR) -> alpha in place
                                              const int* __restrict__ colsrc,
                                              const int* __restrict__ rowptr,
                                              const float* __restrict__ bias,
                                              float* __restrict__ out, int N) {
  int lane = threadIdx.x & 63;
  int n = blockIdx.x * 4 + (threadIdx.x >> 6);
  if (n >= N) return;
  int start = rowptr[n];
  int deg = rowptr[n + 1] - start;
  int h = lane & 7, esub = lane >> 3;
  float adst_h = a_dst[n * H + h];
  float asrc_h = a_src[n * H + h];

  // pass A: alpha = leaky(a_src[src]+a_dst[n]+ae); per-head max; raw ae sum (for self-loop mean)
  float pmax = -1e30f, psum = 0.f;
  for (int j0 = 0; j0 < deg; j0 += 8) {
    int j = j0 + esub;
    if (j < deg) {
      int src = colsrc[start + j];
      float aev = apre[(size_t)(start + j) * H + h];
      psum += aev;
      float al = a_src[src * H + h] + adst_h + aev;
      al = (al >= 0.f) ? al : NEG_SLOPE * al;
      apre[(size_t)(start + j) * H + h] = al;
      pmax = fmaxf(pmax, al);
    }
  }
#pragma unroll
  for (int m = 8; m <= 32; m <<= 1) {
    pmax = fmaxf(pmax, __shfl_xor(pmax, m, 64));
    psum += __shfl_xor(psum, m, 64);
  }
  float aself = asrc_h + adst_h + psum / fmaxf((float)deg, 1.f);
  aself = (aself >= 0.f) ? aself : NEG_SLOPE * aself;
  float amax = fmaxf(pmax, aself);
  __threadfence_block();   // make pass-A alpha stores visible to other lanes' loads

  // pass B: denom
  float pden = 0.f;
  for (int j0 = 0; j0 < deg; j0 += 8) {
    int j = j0 + esub;
    if (j < deg) {
      float al = apre[(size_t)(start + j) * H + h];
      pden += __expf(al - amax);
    }
  }
#pragma unroll
  for (int m = 8; m <= 32; m <<= 1) pden += __shfl_xor(pden, m, 64);
  float exs = __expf(aself - amax);
  float inv = 1.f / (pden + exs);
  float wself = exs * inv;

  // pass C: lane l -> channels 4l..4l+3, head = l>>3
  int hc = lane >> 3;
  float amax_c  = __shfl(amax, hc, 64);
  float inv_c   = __shfl(inv, hc, 64);
  float wself_c = __shfl(wself, hc, 64);
  float4 acc = ((const float4*)&xh[(size_t)n * HC])[lane];
  acc.x *= wself_c; acc.y *= wself_c; acc.z *= wself_c; acc.w *= wself_c;
#pragma unroll 4
  for (int j = 0; j < deg; ++j) {
    int src = colsrc[start + j];                       // broadcast
    float al = apre[(size_t)(start + j) * H + hc];     // broadcast per 8 lanes
    float wgt = __expf(al - amax_c) * inv_c;
    float4 v = ((const float4*)&xh[(size_t)src * HC])[lane];
    acc.x = fmaf(v.x, wgt, acc.x);
    acc.y = fmaf(v.y, wgt, acc.y);
    acc.z = fmaf(v.z, wgt, acc.z);
    acc.w = fmaf(v.w, wgt, acc.w);
  }
  // head mean: lanes l, l^8, l^16, l^32 hold same channel-in-head, different heads
#pragma unroll
  for (int m = 8; m <= 32; m <<= 1) {
    acc.x += __shfl_xor(acc.x, m, 64);
    acc.y += __shfl_xor(acc.y, m, 64);
    acc.z += __shfl_xor(acc.z, m, 64);
    acc.w += __shfl_xor(acc.w, m, 64);
  }
  if (lane < 8) {
    float4 b = ((const float4*)bias)[lane];
    float4 o;
    o.x = acc.x * 0.125f + b.x;
    o.y = acc.y * 0.125f + b.y;
    o.z = acc.z * 0.125f + b.z;
    o.w = acc.w * 0.125f + b.w;
    ((float4*)&out[(size_t)n * C])[lane] = o;
  }
}

extern "C" void kernel_launch(void* const* d_in, const int* in_sizes, int n_in,
                              void* d_out, int out_size, void* d_ws, size_t ws_size,
                              hipStream_t stream) {
  const float* x        = (const float*)d_in[0];
  const int*   ei       = (const int*)d_in[1];
  const float* ea       = (const float*)d_in[2];
  const float* W        = (const float*)d_in[3];
  const float* W_edge   = (const float*)d_in[4];
  const float* att_src  = (const float*)d_in[5];
  const float* att_dst  = (const float*)d_in[6];
  const float* att_edge = (const float*)d_in[7];
  const float* bias     = (const float*)d_in[8];
  float* out = (float*)d_out;

  int N = in_sizes[0] / FIN;
  int E = in_sizes[1] / 2;
  int nb = (N + 255) / 256;

  char* ws = (char*)d_ws;
  auto take = [&](size_t bytes) {
    char* p = ws;
    ws += (bytes + 255) & ~(size_t)255;
    return p;
  };
  float* xh     = (float*)take((size_t)N * HC * 4);
  float* a_src  = (float*)take((size_t)N * H * 4);
  float* a_dst  = (float*)take((size_t)N * H * 4);
  float* a_edge = (float*)take((size_t)E * H * 4);
  float* apre   = (float*)take((size_t)E * H * 4);
  float* Mbuf   = (float*)take(FE * H * 4);
  int*   deg    = (int*)take((size_t)N * 4);
  int*   rowptr = (int*)take((size_t)(N + 1) * 4);
  int*   wo     = (int*)take((size_t)N * 4);
  int*   colsrc = (int*)take((size_t)E * 4);
  int*   bsum   = (int*)take((size_t)nb * 4);
  int*   boff   = (int*)take((size_t)nb * 4);

  hipMemsetAsync(deg, 0, (size_t)N * 4, stream);
  k_M<<<1, 128, 0, stream>>>(W_edge, att_edge, Mbuf);
  k_xh<<<dim3((N + 63) / 64, HC / 64), 256, 0, stream>>>(x, W, xh, N);
  k_att<<<N, 256, 0, stream>>>(xh, att_src, att_dst, a_src, a_dst, N);
  k_edge<<<(E + 255) / 256, 256, 0, stream>>>(ei, ea, Mbuf, a_edge, deg, E);
  k_scan1<<<nb, 256, 0, stream>>>(deg, bsum, N);
  k_scan2<<<1, 256, 0, stream>>>(bsum, boff, nb);
  k_scan3<<<nb, 256, 0, stream>>>(deg, boff, rowptr, wo, N, E);
  k_scatter<<<(E + 255) / 256, 256, 0, stream>>>(ei, a_edge, wo, colsrc, apre, E);
  k_node<<<(N + 3) / 4, 256, 0, stream>>>(xh, a_src, a_dst, apre, colsrc, rowptr, bias, out, N);
}

// Round 3
// 344.787 us; speedup vs baseline: 1.8533x; 1.2665x over previous
//
#include <hip/hip_runtime.h>
#include <math.h>

#define H 8
#define C 32
#define HC 256      // H*C
#define FE 16
#define FIN 128
#define NEG_SLOPE 0.2f

__device__ __forceinline__ unsigned short f2bf(float f) {
  union { float f; unsigned int u; } a; a.f = f;
  unsigned int r = a.u;
  unsigned int lsb = (r >> 16) & 1u;
  r += 0x7fffu + lsb;               // round-to-nearest-even
  return (unsigned short)(r >> 16);
}
__device__ __forceinline__ float bf2f(unsigned short s) {
  union { unsigned int u; float f; } a; a.u = ((unsigned int)s) << 16;
  return a.f;
}

// ---------------- M[f][h] = sum_c W_edge[(h*C+c)*FE+f] * att_edge[h*C+c] ----------------
__global__ void k_M(const float* __restrict__ W_edge, const float* __restrict__ att_edge,
                    float* __restrict__ M) {
  int t = threadIdx.x;          // 128 threads: f = t>>3, h = t&7
  int f = t >> 3, h = t & 7;
  float acc = 0.f;
#pragma unroll
  for (int c = 0; c < C; ++c)
    acc += W_edge[(h * C + c) * FE + f] * att_edge[h * C + c];
  M[f * H + h] = acc;
}

// ---------------- xh = x @ W.T, 128x128 tiles, 8x8/thread; epilogue: bf16 store + a_src/a_dst ----------------
__global__ __launch_bounds__(256) void k_xh(const float* __restrict__ x,
                                            const float* __restrict__ W,
                                            const float* __restrict__ att_src,
                                            const float* __restrict__ att_dst,
                                            unsigned short* __restrict__ xhb,
                                            float* __restrict__ a_src,
                                            float* __restrict__ a_dst, int N) {
  __shared__ float As[16][132];
  __shared__ float Bs[16][132];
  int t = threadIdx.x;
  int rg = t >> 4;            // 0..15 row group (8 rows each)
  int cg = t & 15;            // 0..15 col group (8 cols each)
  int rb = blockIdx.x * 128;
  int cb = blockIdx.y * 128;
  int lr = t >> 2;            // staging row 0..63
  int lk = (t & 3) * 4;       // staging k 0,4,8,12

  float acc[8][8] = {};
  for (int k0 = 0; k0 < FIN; k0 += 16) {
#pragma unroll
    for (int half = 0; half < 2; ++half) {
      int row = half * 64 + lr;
      float4 va = make_float4(0.f, 0.f, 0.f, 0.f);
      if (rb + row < N) va = *(const float4*)&x[(size_t)(rb + row) * FIN + k0 + lk];
      As[lk + 0][row] = va.x; As[lk + 1][row] = va.y; As[lk + 2][row] = va.z; As[lk + 3][row] = va.w;
      float4 vb = *(const float4*)&W[(size_t)(cb + row) * FIN + k0 + lk];
      Bs[lk + 0][row] = vb.x; Bs[lk + 1][row] = vb.y; Bs[lk + 2][row] = vb.z; Bs[lk + 3][row] = vb.w;
    }
    __syncthreads();
#pragma unroll
    for (int k = 0; k < 16; ++k) {
      float4 a0 = *(const float4*)&As[k][rg * 8];
      float4 a1 = *(const float4*)&As[k][rg * 8 + 4];
      float4 b0 = *(const float4*)&Bs[k][cg * 8];
      float4 b1 = *(const float4*)&Bs[k][cg * 8 + 4];
      float av[8] = {a0.x, a0.y, a0.z, a0.w, a1.x, a1.y, a1.z, a1.w};
      float bv[8] = {b0.x, b0.y, b0.z, b0.w, b1.x, b1.y, b1.z, b1.w};
#pragma unroll
      for (int i = 0; i < 8; ++i)
#pragma unroll
        for (int j = 0; j < 8; ++j) acc[i][j] = fmaf(av[i], bv[j], acc[i][j]);
    }
    __syncthreads();
  }

  // epilogue: bf16 store + per-head att partial dots
  float asv[8], adv[8];
#pragma unroll
  for (int j = 0; j < 8; ++j) {
    asv[j] = att_src[cb + cg * 8 + j];
    adv[j] = att_dst[cb + cg * 8 + j];
  }
  int head = blockIdx.y * 4 + (cg >> 2);
#pragma unroll
  for (int i = 0; i < 8; ++i) {
    int r = rb + rg * 8 + i;
    if (r >= N) continue;
    // pack 8 bf16 -> uint4
    unsigned int p0 = (unsigned int)f2bf(acc[i][0]) | ((unsigned int)f2bf(acc[i][1]) << 16);
    unsigned int p1 = (unsigned int)f2bf(acc[i][2]) | ((unsigned int)f2bf(acc[i][3]) << 16);
    unsigned int p2 = (unsigned int)f2bf(acc[i][4]) | ((unsigned int)f2bf(acc[i][5]) << 16);
    unsigned int p3 = (unsigned int)f2bf(acc[i][6]) | ((unsigned int)f2bf(acc[i][7]) << 16);
    uint4 pk = make_uint4(p0, p1, p2, p3);
    *(uint4*)&xhb[(size_t)r * HC + cb + cg * 8] = pk;
    float ps = 0.f, pd = 0.f;
#pragma unroll
    for (int j = 0; j < 8; ++j) { ps = fmaf(acc[i][j], asv[j], ps); pd = fmaf(acc[i][j], adv[j], pd); }
    // reduce across 4 threads (cg within head quad): lanes xor 1,2
    ps += __shfl_xor(ps, 1, 64); ps += __shfl_xor(ps, 2, 64);
    pd += __shfl_xor(pd, 1, 64); pd += __shfl_xor(pd, 2, 64);
    if ((t & 3) == 0) {
      a_src[r * H + head] = ps;
      a_dst[r * H + head] = pd;
    }
  }
}

// ---------------- degree histogram ----------------
__global__ __launch_bounds__(256) void k_deg(const int* __restrict__ ei,
                                             int* __restrict__ deg, int E) {
  int e = blockIdx.x * 256 + threadIdx.x;
  if (e < E) atomicAdd(&deg[ei[E + e]], 1);
}

// ---------------- hierarchical scan ----------------
__global__ __launch_bounds__(256) void k_scan1(const int* __restrict__ deg,
                                               int* __restrict__ bsum, int N) {
  int t = threadIdx.x;
  int i = blockIdx.x * 256 + t;
  int v = (i < N) ? deg[i] : 0;
#pragma unroll
  for (int m = 1; m < 64; m <<= 1) v += __shfl_xor(v, m, 64);
  __shared__ int wsum[4];
  if ((t & 63) == 0) wsum[t >> 6] = v;
  __syncthreads();
  if (t == 0) bsum[blockIdx.x] = wsum[0] + wsum[1] + wsum[2] + wsum[3];
}

__global__ __launch_bounds__(256) void k_scan2(const int* __restrict__ bsum,
                                               int* __restrict__ boff, int nb) {
  __shared__ int buf[256];
  int t = threadIdx.x;
  int v = (t < nb) ? bsum[t] : 0;
  buf[t] = v;
  __syncthreads();
  for (int off = 1; off < 256; off <<= 1) {
    int y = (t >= off) ? buf[t - off] : 0;
    __syncthreads();
    buf[t] += y;
    __syncthreads();
  }
  if (t < nb) boff[t] = buf[t] - v;   // exclusive
}

__global__ __launch_bounds__(256) void k_scan3(const int* __restrict__ deg,
                                               const int* __restrict__ boff,
                                               int* __restrict__ rowptr,
                                               int* __restrict__ wo, int N, int E) {
  __shared__ int buf[256];
  int t = threadIdx.x;
  int i = blockIdx.x * 256 + t;
  int v = (i < N) ? deg[i] : 0;
  buf[t] = v;
  __syncthreads();
  for (int off = 1; off < 256; off <<= 1) {
    int y = (t >= off) ? buf[t - off] : 0;
    __syncthreads();
    buf[t] += y;
    __syncthreads();
  }
  if (i < N) {
    int ex = boff[blockIdx.x] + buf[t] - v;
    rowptr[i] = ex;
    wo[i] = ex;
  }
  if (i == 0) rowptr[N] = E;
}

// ---------------- per-edge: a_edge = ea @ M, scattered directly into CSR ----------------
__global__ __launch_bounds__(256) void k_edge_scatter(const int* __restrict__ ei,
                                                      const float* __restrict__ ea,
                                                      const float* __restrict__ M,
                                                      int* __restrict__ wo,
                                                      int* __restrict__ colsrc,
                                                      float* __restrict__ apre, int E) {
  __shared__ float Ms[FE * H];
  int t = threadIdx.x;
  if (t < FE * H) Ms[t] = M[t];
  __syncthreads();
  int e = blockIdx.x * 256 + t;
  if (e >= E) return;
  int s = ei[e], d = ei[E + e];
  const float4* p = (const float4*)&ea[(size_t)e * FE];
  float4 v0 = p[0], v1 = p[1], v2 = p[2], v3 = p[3];
  float eav[FE] = {v0.x, v0.y, v0.z, v0.w, v1.x, v1.y, v1.z, v1.w,
                   v2.x, v2.y, v2.z, v2.w, v3.x, v3.y, v3.z, v3.w};
  float o[H];
#pragma unroll
  for (int h = 0; h < H; ++h) {
    float acc = 0.f;
#pragma unroll
    for (int f = 0; f < FE; ++f) acc += eav[f] * Ms[f * H + h];
    o[h] = acc;
  }
  int pos = atomicAdd(&wo[d], 1);
  colsrc[pos] = s;
  float4* q = (float4*)&apre[(size_t)pos * H];
  q[0] = make_float4(o[0], o[1], o[2], o[3]);
  q[1] = make_float4(o[4], o[5], o[6], o[7]);
}

// ---------------- wave-per-node: flash-style single-pass softmax + bf16 gather ----------------
__global__ __launch_bounds__(256) void k_node(const unsigned short* __restrict__ xhb,
                                              const float* __restrict__ a_src,
                                              const float* __restrict__ a_dst,
                                              const float* __restrict__ apre,   // raw a_edge (CSR)
                                              const int* __restrict__ colsrc,
                                              const int* __restrict__ rowptr,
                                              const float* __restrict__ bias,
                                              float* __restrict__ out, int N) {
  int lane = threadIdx.x & 63;
  int n = blockIdx.x * 4 + (threadIdx.x >> 6);
  if (n >= N) return;
  int start = rowptr[n];
  int deg = rowptr[n + 1] - start;
  int hc = lane >> 3;                    // head for this lane's channels & softmax state
  float adst = a_dst[n * H + hc];
  float asrc = a_src[n * H + hc];

  float m = -1e30f, l = 0.f, psum = 0.f;
  float ax = 0.f, ay = 0.f, az = 0.f, aw = 0.f;

#pragma unroll 4
  for (int j = 0; j < deg; ++j) {
    int src = colsrc[start + j];                      // wave-uniform
    float ae = apre[(size_t)(start + j) * H + hc];    // 8 distinct, broadcast
    psum += ae;
    float al = a_src[src * H + hc] + adst + ae;
    al = (al >= 0.f) ? al : NEG_SLOPE * al;
    float nm = fmaxf(m, al);
    float s = __expf(m - nm);
    float w = __expf(al - nm);
    m = nm;
    l = fmaf(l, s, w);
    ushort4 u = *(const ushort4*)&xhb[(size_t)src * HC + lane * 4];
    ax = fmaf(ax, s, w * bf2f(u.x));
    ay = fmaf(ay, s, w * bf2f(u.y));
    az = fmaf(az, s, w * bf2f(u.z));
    aw = fmaf(aw, s, w * bf2f(u.w));
  }

  // self loop (attr = mean of incoming raw a_edge)
  float aself = asrc + adst + psum / fmaxf((float)deg, 1.f);
  aself = (aself >= 0.f) ? aself : NEG_SLOPE * aself;
  {
    float nm = fmaxf(m, aself);
    float s = __expf(m - nm);
    float w = __expf(aself - nm);
    m = nm;
    l = fmaf(l, s, w);
    ushort4 u = *(const ushort4*)&xhb[(size_t)n * HC + lane * 4];
    ax = fmaf(ax, s, w * bf2f(u.x));
    ay = fmaf(ay, s, w * bf2f(u.y));
    az = fmaf(az, s, w * bf2f(u.z));
    aw = fmaf(aw, s, w * bf2f(u.w));
  }
  float inv = 1.f / l;
  ax *= inv; ay *= inv; az *= inv; aw *= inv;

  // head mean across lanes l^8, l^16, l^32
#pragma unroll
  for (int mm = 8; mm <= 32; mm <<= 1) {
    ax += __shfl_xor(ax, mm, 64);
    ay += __shfl_xor(ay, mm, 64);
    az += __shfl_xor(az, mm, 64);
    aw += __shfl_xor(aw, mm, 64);
  }
  if (lane < 8) {
    float4 b = ((const float4*)bias)[lane];
    float4 o;
    o.x = ax * 0.125f + b.x;
    o.y = ay * 0.125f + b.y;
    o.z = az * 0.125f + b.z;
    o.w = aw * 0.125f + b.w;
    ((float4*)&out[(size_t)n * C])[lane] = o;
  }
}

extern "C" void kernel_launch(void* const* d_in, const int* in_sizes, int n_in,
                              void* d_out, int out_size, void* d_ws, size_t ws_size,
                              hipStream_t stream) {
  const float* x        = (const float*)d_in[0];
  const int*   ei       = (const int*)d_in[1];
  const float* ea       = (const float*)d_in[2];
  const float* W        = (const float*)d_in[3];
  const float* W_edge   = (const float*)d_in[4];
  const float* att_src  = (const float*)d_in[5];
  const float* att_dst  = (const float*)d_in[6];
  const float* att_edge = (const float*)d_in[7];
  const float* bias     = (const float*)d_in[8];
  float* out = (float*)d_out;

  int N = in_sizes[0] / FIN;
  int E = in_sizes[1] / 2;
  int nb = (N + 255) / 256;

  char* ws = (char*)d_ws;
  auto take = [&](size_t bytes) {
    char* p = ws;
    ws += (bytes + 255) & ~(size_t)255;
    return p;
  };
  unsigned short* xhb = (unsigned short*)take((size_t)N * HC * 2);
  float* a_src  = (float*)take((size_t)N * H * 4);
  float* a_dst  = (float*)take((size_t)N * H * 4);
  float* apre   = (float*)take((size_t)E * H * 4);
  float* Mbuf   = (float*)take(FE * H * 4);
  int*   deg    = (int*)take((size_t)N * 4);
  int*   rowptr = (int*)take((size_t)(N + 1) * 4);
  int*   wo     = (int*)take((size_t)N * 4);
  int*   colsrc = (int*)take((size_t)E * 4);
  int*   bsum   = (int*)take((size_t)nb * 4);
  int*   boff   = (int*)take((size_t)nb * 4);

  hipMemsetAsync(deg, 0, (size_t)N * 4, stream);
  k_M<<<1, 128, 0, stream>>>(W_edge, att_edge, Mbuf);
  k_deg<<<(E + 255) / 256, 256, 0, stream>>>(ei, deg, E);
  k_xh<<<dim3((N + 127) / 128, HC / 128), 256, 0, stream>>>(x, W, att_src, att_dst, xhb, a_src, a_dst, N);
  k_scan1<<<nb, 256, 0, stream>>>(deg, bsum, N);
  k_scan2<<<1, 256, 0, stream>>>(bsum, boff, nb);
  k_scan3<<<nb, 256, 0, stream>>>(deg, boff, rowptr, wo, N, E);
  k_edge_scatter<<<(E + 255) / 256, 256, 0, stream>>>(ei, ea, Mbuf, wo, colsrc, apre, E);
  k_node<<<(N + 3) / 4, 256, 0, stream>>>(xhb, a_src, a_dst, apre, colsrc, rowptr, bias, out, N);
}

// Round 4
// 312.991 us; speedup vs baseline: 2.0416x; 1.1016x over previous
//
#include <hip/hip_runtime.h>
#include <math.h>

#define H 8
#define C 32
#define HC 256      // H*C
#define FE 16
#define FIN 128
#define NEG_SLOPE 0.2f

typedef __attribute__((ext_vector_type(8))) short bf16x8;
typedef __attribute__((ext_vector_type(4))) float f32x4;

__device__ __forceinline__ unsigned short f2bf(float f) {
  unsigned int u = __float_as_uint(f);
  unsigned int lsb = (u >> 16) & 1u;
  u += 0x7fffu + lsb;               // round-to-nearest-even
  return (unsigned short)(u >> 16);
}
__device__ __forceinline__ float bf2f(unsigned short s) {
  return __uint_as_float(((unsigned int)s) << 16);
}

// split 8 fp32 into hi (truncated bf16) + lo (RNE bf16 of residual)
__device__ __forceinline__ void split8(const float* v, bf16x8& hi, bf16x8& lo) {
#pragma unroll
  for (int i = 0; i < 8; ++i) {
    unsigned int u = __float_as_uint(v[i]);
    unsigned int hu = u & 0xffff0000u;
    float r = v[i] - __uint_as_float(hu);
    hi[i] = (short)(hu >> 16);
    lo[i] = (short)f2bf(r);
  }
}

// ---------------- xh^T = W @ x^T via MFMA split-bf16 (3 passes, fp32-grade accuracy) ----------------
// Block: 128 channels (blockIdx.y half) x 128 nodes. Wave w: nodes [w*32, w*32+32), all 128 ch.
// Zero LDS, zero barriers: A/B fragments are 32B contiguous row chunks -> register-direct.
__global__ __launch_bounds__(256) void k_xh(const float* __restrict__ x,
                                            const float* __restrict__ W,
                                            const float* __restrict__ att_src,
                                            const float* __restrict__ att_dst,
                                            unsigned short* __restrict__ xhb,
                                            float* __restrict__ a_src,
                                            float* __restrict__ a_dst, int N) {
  int t = threadIdx.x;
  int w = t >> 6, lane = t & 63;
  int n15 = lane & 15, q = lane >> 4;
  int nodeBase = blockIdx.x * 128 + w * 32;      // + nt*16 + n15
  int chBase = blockIdx.y * 128;                 // + mt*16 + (row idx)

  f32x4 acc[8][2];
#pragma unroll
  for (int mt = 0; mt < 8; ++mt)
#pragma unroll
    for (int nt = 0; nt < 2; ++nt) acc[mt][nt] = (f32x4)(0.f);

  for (int ks = 0; ks < 4; ++ks) {
    int kOff = ks * 32 + q * 8;
    // B fragments: x rows (nodes), 8 contiguous k
    bf16x8 Bhi[2], Blo[2];
#pragma unroll
    for (int nt = 0; nt < 2; ++nt) {
      int node = nodeBase + nt * 16 + n15;
      int rn = (node < N) ? node : (N - 1);
      const float* px = &x[(size_t)rn * FIN + kOff];
      float vb[8];
      *(float4*)&vb[0] = *(const float4*)px;
      *(float4*)&vb[4] = *(const float4*)(px + 4);
      split8(vb, Bhi[nt], Blo[nt]);
    }
#pragma unroll
    for (int mt = 0; mt < 8; ++mt) {
      const float* pw = &W[(size_t)(chBase + mt * 16 + n15) * FIN + kOff];
      float va[8];
      *(float4*)&va[0] = *(const float4*)pw;
      *(float4*)&va[4] = *(const float4*)(pw + 4);
      bf16x8 Ahi, Alo;
      split8(va, Ahi, Alo);
#pragma unroll
      for (int nt = 0; nt < 2; ++nt) {
        acc[mt][nt] = __builtin_amdgcn_mfma_f32_16x16x32_bf16(Ahi, Bhi[nt], acc[mt][nt], 0, 0, 0);
        acc[mt][nt] = __builtin_amdgcn_mfma_f32_16x16x32_bf16(Ahi, Blo[nt], acc[mt][nt], 0, 0, 0);
        acc[mt][nt] = __builtin_amdgcn_mfma_f32_16x16x32_bf16(Alo, Bhi[nt], acc[mt][nt], 0, 0, 0);
      }
    }
  }

  // Epilogue. C/D layout: col(lane&15)=node, row=q*4+reg = channel within tile.
  float ps[2][4] = {{0.f,0.f,0.f,0.f},{0.f,0.f,0.f,0.f}};
  float pd[2][4] = {{0.f,0.f,0.f,0.f},{0.f,0.f,0.f,0.f}};
#pragma unroll
  for (int mt = 0; mt < 8; ++mt) {
    int hl = mt >> 1;
#pragma unroll
    for (int r = 0; r < 4; ++r) {
      int ch = chBase + mt * 16 + q * 4 + r;
      float as_c = att_src[ch], ad_c = att_dst[ch];
#pragma unroll
      for (int nt = 0; nt < 2; ++nt) {
        float val = acc[mt][nt][r];
        ps[nt][hl] = fmaf(val, as_c, ps[nt][hl]);
        pd[nt][hl] = fmaf(val, ad_c, pd[nt][hl]);
      }
    }
    // bf16 store: 4 consecutive channels of one node -> 8B
#pragma unroll
    for (int nt = 0; nt < 2; ++nt) {
      int node = nodeBase + nt * 16 + n15;
      if (node < N) {
        ushort4 us;
        us.x = f2bf(acc[mt][nt][0]); us.y = f2bf(acc[mt][nt][1]);
        us.z = f2bf(acc[mt][nt][2]); us.w = f2bf(acc[mt][nt][3]);
        *(ushort4*)&xhb[(size_t)node * HC + chBase + mt * 16 + q * 4] = us;
      }
    }
  }
  // reduce att partials across quads (q dimension)
#pragma unroll
  for (int nt = 0; nt < 2; ++nt)
#pragma unroll
    for (int hl = 0; hl < 4; ++hl) {
      ps[nt][hl] += __shfl_xor(ps[nt][hl], 16, 64);
      ps[nt][hl] += __shfl_xor(ps[nt][hl], 32, 64);
      pd[nt][hl] += __shfl_xor(pd[nt][hl], 16, 64);
      pd[nt][hl] += __shfl_xor(pd[nt][hl], 32, 64);
    }
  if (q == 0) {
#pragma unroll
    for (int nt = 0; nt < 2; ++nt) {
      int node = nodeBase + nt * 16 + n15;
      if (node < N) {
        *(float4*)&a_src[node * H + blockIdx.y * 4] = make_float4(ps[nt][0], ps[nt][1], ps[nt][2], ps[nt][3]);
        *(float4*)&a_dst[node * H + blockIdx.y * 4] = make_float4(pd[nt][0], pd[nt][1], pd[nt][2], pd[nt][3]);
      }
    }
  }
}

// ---------------- degree histogram + per-edge rank within dst ----------------
__global__ __launch_bounds__(256) void k_deg(const int* __restrict__ ei,
                                             int* __restrict__ deg,
                                             int* __restrict__ rank, int E) {
  int e = blockIdx.x * 256 + threadIdx.x;
  if (e < E) rank[e] = atomicAdd(&deg[ei[E + e]], 1);
}

// ---------------- hierarchical scan ----------------
__global__ __launch_bounds__(256) void k_scan1(const int* __restrict__ deg,
                                               int* __restrict__ bsum, int N) {
  int t = threadIdx.x;
  int i = blockIdx.x * 256 + t;
  int v = (i < N) ? deg[i] : 0;
#pragma unroll
  for (int m = 1; m < 64; m <<= 1) v += __shfl_xor(v, m, 64);
  __shared__ int wsum[4];
  if ((t & 63) == 0) wsum[t >> 6] = v;
  __syncthreads();
  if (t == 0) bsum[blockIdx.x] = wsum[0] + wsum[1] + wsum[2] + wsum[3];
}

__global__ __launch_bounds__(256) void k_scan2(const int* __restrict__ bsum,
                                               int* __restrict__ boff, int nb) {
  __shared__ int buf[256];
  int t = threadIdx.x;
  int v = (t < nb) ? bsum[t] : 0;
  buf[t] = v;
  __syncthreads();
  for (int off = 1; off < 256; off <<= 1) {
    int y = (t >= off) ? buf[t - off] : 0;
    __syncthreads();
    buf[t] += y;
    __syncthreads();
  }
  if (t < nb) boff[t] = buf[t] - v;   // exclusive
}

__global__ __launch_bounds__(256) void k_scan3(const int* __restrict__ deg,
                                               const int* __restrict__ boff,
                                               int* __restrict__ rowptr, int N, int E) {
  __shared__ int buf[256];
  int t = threadIdx.x;
  int i = blockIdx.x * 256 + t;
  int v = (i < N) ? deg[i] : 0;
  buf[t] = v;
  __syncthreads();
  for (int off = 1; off < 256; off <<= 1) {
    int y = (t >= off) ? buf[t - off] : 0;
    __syncthreads();
    buf[t] += y;
    __syncthreads();
  }
  if (i < N) rowptr[i] = boff[blockIdx.x] + buf[t] - v;
  if (i == 0) rowptr[N] = E;
}

// ---------------- per-edge: a_edge = ea @ M, scattered into CSR slot (bf16), no atomics ----------------
__global__ __launch_bounds__(256) void k_edge_scatter(const int* __restrict__ ei,
                                                      const float* __restrict__ ea,
                                                      const float* __restrict__ W_edge,
                                                      const float* __restrict__ att_edge,
                                                      const int* __restrict__ rowptr,
                                                      const int* __restrict__ rank,
                                                      int* __restrict__ colsrc,
                                                      unsigned short* __restrict__ apre16, int E) {
  __shared__ float Ms[FE * H];
  int t = threadIdx.x;
  if (t < FE * H) {          // M[f][h] = sum_c W_edge[(h*C+c)*FE+f] * att_edge[h*C+c]
    int f = t >> 3, h = t & 7;
    float acc = 0.f;
#pragma unroll
    for (int c = 0; c < C; ++c)
      acc += W_edge[(h * C + c) * FE + f] * att_edge[h * C + c];
    Ms[f * H + h] = acc;
  }
  __syncthreads();
  int e = blockIdx.x * 256 + t;
  if (e >= E) return;
  int s = ei[e], d = ei[E + e];
  const float4* p = (const float4*)&ea[(size_t)e * FE];
  float4 v0 = p[0], v1 = p[1], v2 = p[2], v3 = p[3];
  float eav[FE] = {v0.x, v0.y, v0.z, v0.w, v1.x, v1.y, v1.z, v1.w,
                   v2.x, v2.y, v2.z, v2.w, v3.x, v3.y, v3.z, v3.w};
  float o[H];
#pragma unroll
  for (int h = 0; h < H; ++h) {
    float acc = 0.f;
#pragma unroll
    for (int f = 0; f < FE; ++f) acc += eav[f] * Ms[f * H + h];
    o[h] = acc;
  }
  int pos = rowptr[d] + rank[e];
  colsrc[pos] = s;
  uint4 pk;
  pk.x = (unsigned int)f2bf(o[0]) | ((unsigned int)f2bf(o[1]) << 16);
  pk.y = (unsigned int)f2bf(o[2]) | ((unsigned int)f2bf(o[3]) << 16);
  pk.z = (unsigned int)f2bf(o[4]) | ((unsigned int)f2bf(o[5]) << 16);
  pk.w = (unsigned int)f2bf(o[6]) | ((unsigned int)f2bf(o[7]) << 16);
  *(uint4*)&apre16[(size_t)pos * H] = pk;
}

// ---------------- wave-per-node: flash-style single-pass softmax + bf16 gather ----------------
__global__ __launch_bounds__(256) void k_node(const unsigned short* __restrict__ xhb,
                                              const float* __restrict__ a_src,
                                              const float* __restrict__ a_dst,
                                              const unsigned short* __restrict__ apre16,
                                              const int* __restrict__ colsrc,
                                              const int* __restrict__ rowptr,
                                              const float* __restrict__ bias,
                                              float* __restrict__ out, int N) {
  int lane = threadIdx.x & 63;
  int n = blockIdx.x * 4 + (threadIdx.x >> 6);
  if (n >= N) return;
  int start = rowptr[n];
  int deg = rowptr[n + 1] - start;
  int hc = lane >> 3;                    // head for this lane's channels & softmax state
  float adst = a_dst[n * H + hc];
  float asrc = a_src[n * H + hc];

  float m = -1e30f, l = 0.f, psum = 0.f;
  float ax = 0.f, ay = 0.f, az = 0.f, aw = 0.f;

#pragma unroll 4
  for (int j = 0; j < deg; ++j) {
    int src = colsrc[start + j];                             // wave-uniform
    float ae = bf2f(apre16[(size_t)(start + j) * H + hc]);   // 8 distinct, broadcast
    psum += ae;
    float al = a_src[src * H + hc] + adst + ae;
    al = (al >= 0.f) ? al : NEG_SLOPE * al;
    float nm = fmaxf(m, al);
    float s = __expf(m - nm);
    float w = __expf(al - nm);
    m = nm;
    l = fmaf(l, s, w);
    ushort4 u = *(const ushort4*)&xhb[(size_t)src * HC + lane * 4];
    ax = fmaf(ax, s, w * bf2f(u.x));
    ay = fmaf(ay, s, w * bf2f(u.y));
    az = fmaf(az, s, w * bf2f(u.z));
    aw = fmaf(aw, s, w * bf2f(u.w));
  }

  // self loop (attr = mean of incoming raw a_edge)
  float aself = asrc + adst + psum / fmaxf((float)deg, 1.f);
  aself = (aself >= 0.f) ? aself : NEG_SLOPE * aself;
  {
    float nm = fmaxf(m, aself);
    float s = __expf(m - nm);
    float w = __expf(aself - nm);
    m = nm;
    l = fmaf(l, s, w);
    ushort4 u = *(const ushort4*)&xhb[(size_t)n * HC + lane * 4];
    ax = fmaf(ax, s, w * bf2f(u.x));
    ay = fmaf(ay, s, w * bf2f(u.y));
    az = fmaf(az, s, w * bf2f(u.z));
    aw = fmaf(aw, s, w * bf2f(u.w));
  }
  float inv = 1.f / l;
  ax *= inv; ay *= inv; az *= inv; aw *= inv;

  // head mean across lanes l^8, l^16, l^32
#pragma unroll
  for (int mm = 8; mm <= 32; mm <<= 1) {
    ax += __shfl_xor(ax, mm, 64);
    ay += __shfl_xor(ay, mm, 64);
    az += __shfl_xor(az, mm, 64);
    aw += __shfl_xor(aw, mm, 64);
  }
  if (lane < 8) {
    float4 b = ((const float4*)bias)[lane];
    float4 o;
    o.x = ax * 0.125f + b.x;
    o.y = ay * 0.125f + b.y;
    o.z = az * 0.125f + b.z;
    o.w = aw * 0.125f + b.w;
    ((float4*)&out[(size_t)n * C])[lane] = o;
  }
}

extern "C" void kernel_launch(void* const* d_in, const int* in_sizes, int n_in,
                              void* d_out, int out_size, void* d_ws, size_t ws_size,
                              hipStream_t stream) {
  const float* x        = (const float*)d_in[0];
  const int*   ei       = (const int*)d_in[1];
  const float* ea       = (const float*)d_in[2];
  const float* W        = (const float*)d_in[3];
  const float* W_edge   = (const float*)d_in[4];
  const float* att_src  = (const float*)d_in[5];
  const float* att_dst  = (const float*)d_in[6];
  const float* att_edge = (const float*)d_in[7];
  const float* bias     = (const float*)d_in[8];
  float* out = (float*)d_out;

  int N = in_sizes[0] / FIN;
  int E = in_sizes[1] / 2;
  int nb = (N + 255) / 256;

  char* ws = (char*)d_ws;
  auto take = [&](size_t bytes) {
    char* p = ws;
    ws += (bytes + 255) & ~(size_t)255;
    return p;
  };
  unsigned short* xhb    = (unsigned short*)take((size_t)N * HC * 2);
  float*          a_src  = (float*)take((size_t)N * H * 4);
  float*          a_dst  = (float*)take((size_t)N * H * 4);
  unsigned short* apre16 = (unsigned short*)take((size_t)E * H * 2);
  int*            deg    = (int*)take((size_t)N * 4);
  int*            rowptr = (int*)take((size_t)(N + 1) * 4);
  int*            rank   = (int*)take((size_t)E * 4);
  int*            colsrc = (int*)take((size_t)E * 4);
  int*            bsum   = (int*)take((size_t)nb * 4);
  int*            boff   = (int*)take((size_t)nb * 4);

  hipMemsetAsync(deg, 0, (size_t)N * 4, stream);
  k_deg<<<(E + 255) / 256, 256, 0, stream>>>(ei, deg, rank, E);
  k_xh<<<dim3((N + 127) / 128, 2), 256, 0, stream>>>(x, W, att_src, att_dst, xhb, a_src, a_dst, N);
  k_scan1<<<nb, 256, 0, stream>>>(deg, bsum, N);
  k_scan2<<<1, 256, 0, stream>>>(bsum, boff, nb);
  k_scan3<<<nb, 256, 0, stream>>>(deg, boff, rowptr, N, E);
  k_edge_scatter<<<(E + 255) / 256, 256, 0, stream>>>(ei, ea, W_edge, att_edge, rowptr, rank, colsrc, apre16, E);
  k_node<<<(N + 3) / 4, 256, 0, stream>>>(xhb, a_src, a_dst, apre16, colsrc, rowptr, bias, out, N);
}

// Round 5
// 306.957 us; speedup vs baseline: 2.0817x; 1.0197x over previous
//
#include <hip/hip_runtime.h>
#include <math.h>

#define H 8
#define C 32
#define HC 256      // H*C
#define FE 16
#define FIN 128
#define NEG_SLOPE 0.2f

typedef __attribute__((ext_vector_type(8))) short bf16x8;
typedef __attribute__((ext_vector_type(4))) float f32x4;

__device__ __forceinline__ unsigned short f2bf(float f) {
  unsigned int u = __float_as_uint(f);
  unsigned int lsb = (u >> 16) & 1u;
  u += 0x7fffu + lsb;               // round-to-nearest-even
  return (unsigned short)(u >> 16);
}
__device__ __forceinline__ float bf2f(unsigned short s) {
  return __uint_as_float(((unsigned int)s) << 16);
}

// split 8 fp32 into hi (truncated bf16) + lo (RNE bf16 of residual)
__device__ __forceinline__ void split8(const float* v, bf16x8& hi, bf16x8& lo) {
#pragma unroll
  for (int i = 0; i < 8; ++i) {
    unsigned int u = __float_as_uint(v[i]);
    unsigned int hu = u & 0xffff0000u;
    float r = v[i] - __uint_as_float(hu);
    hi[i] = (short)(hu >> 16);
    lo[i] = (short)f2bf(r);
  }
}

// ---------------- one-off: split W into bf16 hi/lo planes ----------------
__global__ __launch_bounds__(256) void k_wsplit(const float* __restrict__ W,
                                                unsigned short* __restrict__ Whi,
                                                unsigned short* __restrict__ Wlo) {
  int i = blockIdx.x * 256 + threadIdx.x;   // HC*FIN = 32768 total
  float v = W[i];
  unsigned int u = __float_as_uint(v);
  unsigned int hu = u & 0xffff0000u;
  Whi[i] = (unsigned short)(hu >> 16);
  Wlo[i] = f2bf(v - __uint_as_float(hu)) , (unsigned short)0;  // dummy comma? no
}

// (note: expression above fixed below — see k_wsplit2)
__global__ __launch_bounds__(256) void k_wsplit2(const float* __restrict__ W,
                                                 unsigned short* __restrict__ Whi,
                                                 unsigned short* __restrict__ Wlo) {
  int i = blockIdx.x * 256 + threadIdx.x;
  float v = W[i];
  unsigned int u = __float_as_uint(v);
  unsigned int hu = u & 0xffff0000u;
  Whi[i] = (unsigned short)(hu >> 16);
  Wlo[i] = f2bf(v - __uint_as_float(hu));
}

// ---------------- xh^T = W @ x^T via MFMA split-bf16 (3 passes, fp32-grade accuracy) ----------------
__global__ __launch_bounds__(256) void k_xh(const float* __restrict__ x,
                                            const unsigned short* __restrict__ Whi,
                                            const unsigned short* __restrict__ Wlo,
                                            const float* __restrict__ att_src,
                                            const float* __restrict__ att_dst,
                                            unsigned short* __restrict__ xhb,
                                            float* __restrict__ a_src,
                                            float* __restrict__ a_dst, int N) {
  int t = threadIdx.x;
  int w = t >> 6, lane = t & 63;
  int n15 = lane & 15, q = lane >> 4;
  int nodeBase = blockIdx.x * 128 + w * 32;      // + nt*16 + n15
  int chBase = blockIdx.y * 128;                 // + mt*16 + (row idx)

  f32x4 acc[8][2];
#pragma unroll
  for (int mt = 0; mt < 8; ++mt)
#pragma unroll
    for (int nt = 0; nt < 2; ++nt) acc[mt][nt] = (f32x4)(0.f);

  for (int ks = 0; ks < 4; ++ks) {
    int kOff = ks * 32 + q * 8;
    bf16x8 Bhi[2], Blo[2];
#pragma unroll
    for (int nt = 0; nt < 2; ++nt) {
      int node = nodeBase + nt * 16 + n15;
      int rn = (node < N) ? node : (N - 1);
      const float* px = &x[(size_t)rn * FIN + kOff];
      float vb[8];
      *(float4*)&vb[0] = *(const float4*)px;
      *(float4*)&vb[4] = *(const float4*)(px + 4);
      split8(vb, Bhi[nt], Blo[nt]);
    }
#pragma unroll
    for (int mt = 0; mt < 8; ++mt) {
      int widx = ((chBase + mt * 16 + n15) << 7) + kOff;
      bf16x8 Ahi = *(const bf16x8*)&Whi[widx];
      bf16x8 Alo = *(const bf16x8*)&Wlo[widx];
#pragma unroll
      for (int nt = 0; nt < 2; ++nt) {
        acc[mt][nt] = __builtin_amdgcn_mfma_f32_16x16x32_bf16(Ahi, Bhi[nt], acc[mt][nt], 0, 0, 0);
        acc[mt][nt] = __builtin_amdgcn_mfma_f32_16x16x32_bf16(Ahi, Blo[nt], acc[mt][nt], 0, 0, 0);
        acc[mt][nt] = __builtin_amdgcn_mfma_f32_16x16x32_bf16(Alo, Bhi[nt], acc[mt][nt], 0, 0, 0);
      }
    }
  }

  // Epilogue. C/D layout: col(lane&15)=node, row=q*4+reg = channel within tile.
  float ps[2][4] = {{0.f,0.f,0.f,0.f},{0.f,0.f,0.f,0.f}};
  float pd[2][4] = {{0.f,0.f,0.f,0.f},{0.f,0.f,0.f,0.f}};
#pragma unroll
  for (int mt = 0; mt < 8; ++mt) {
    int hl = mt >> 1;
#pragma unroll
    for (int r = 0; r < 4; ++r) {
      int ch = chBase + mt * 16 + q * 4 + r;
      float as_c = att_src[ch], ad_c = att_dst[ch];
#pragma unroll
      for (int nt = 0; nt < 2; ++nt) {
        float val = acc[mt][nt][r];
        ps[nt][hl] = fmaf(val, as_c, ps[nt][hl]);
        pd[nt][hl] = fmaf(val, ad_c, pd[nt][hl]);
      }
    }
#pragma unroll
    for (int nt = 0; nt < 2; ++nt) {
      int node = nodeBase + nt * 16 + n15;
      if (node < N) {
        ushort4 us;
        us.x = f2bf(acc[mt][nt][0]); us.y = f2bf(acc[mt][nt][1]);
        us.z = f2bf(acc[mt][nt][2]); us.w = f2bf(acc[mt][nt][3]);
        *(ushort4*)&xhb[(size_t)node * HC + chBase + mt * 16 + q * 4] = us;
      }
    }
  }
#pragma unroll
  for (int nt = 0; nt < 2; ++nt)
#pragma unroll
    for (int hl = 0; hl < 4; ++hl) {
      ps[nt][hl] += __shfl_xor(ps[nt][hl], 16, 64);
      ps[nt][hl] += __shfl_xor(ps[nt][hl], 32, 64);
      pd[nt][hl] += __shfl_xor(pd[nt][hl], 16, 64);
      pd[nt][hl] += __shfl_xor(pd[nt][hl], 32, 64);
    }
  if (q == 0) {
#pragma unroll
    for (int nt = 0; nt < 2; ++nt) {
      int node = nodeBase + nt * 16 + n15;
      if (node < N) {
        *(float4*)&a_src[node * H + blockIdx.y * 4] = make_float4(ps[nt][0], ps[nt][1], ps[nt][2], ps[nt][3]);
        *(float4*)&a_dst[node * H + blockIdx.y * 4] = make_float4(pd[nt][0], pd[nt][1], pd[nt][2], pd[nt][3]);
      }
    }
  }
}

// ---------------- degree histogram + per-edge rank within dst ----------------
__global__ __launch_bounds__(256) void k_deg(const int* __restrict__ ei,
                                             int* __restrict__ deg,
                                             int* __restrict__ rank, int E) {
  int e = blockIdx.x * 256 + threadIdx.x;
  if (e < E) rank[e] = atomicAdd(&deg[ei[E + e]], 1);
}

// ---------------- hierarchical scan ----------------
__global__ __launch_bounds__(256) void k_scan1(const int* __restrict__ deg,
                                               int* __restrict__ bsum, int N) {
  int t = threadIdx.x;
  int i = blockIdx.x * 256 + t;
  int v = (i < N) ? deg[i] : 0;
#pragma unroll
  for (int m = 1; m < 64; m <<= 1) v += __shfl_xor(v, m, 64);
  __shared__ int wsum[4];
  if ((t & 63) == 0) wsum[t >> 6] = v;
  __syncthreads();
  if (t == 0) bsum[blockIdx.x] = wsum[0] + wsum[1] + wsum[2] + wsum[3];
}

__global__ __launch_bounds__(256) void k_scan2(const int* __restrict__ bsum,
                                               int* __restrict__ boff, int nb) {
  __shared__ int buf[256];
  int t = threadIdx.x;
  int v = (t < nb) ? bsum[t] : 0;
  buf[t] = v;
  __syncthreads();
  for (int off = 1; off < 256; off <<= 1) {
    int y = (t >= off) ? buf[t - off] : 0;
    __syncthreads();
    buf[t] += y;
    __syncthreads();
  }
  if (t < nb) boff[t] = buf[t] - v;   // exclusive
}

__global__ __launch_bounds__(256) void k_scan3(const int* __restrict__ deg,
                                               const int* __restrict__ boff,
                                               int* __restrict__ rowptr, int N, int E) {
  __shared__ int buf[256];
  int t = threadIdx.x;
  int i = blockIdx.x * 256 + t;
  int v = (i < N) ? deg[i] : 0;
  buf[t] = v;
  __syncthreads();
  for (int off = 1; off < 256; off <<= 1) {
    int y = (t >= off) ? buf[t - off] : 0;
    __syncthreads();
    buf[t] += y;
    __syncthreads();
  }
  if (i < N) rowptr[i] = boff[blockIdx.x] + buf[t] - v;
  if (i == 0) rowptr[N] = E;
}

// ---------------- per-edge: a_edge = ea @ M -> 32B CSR record {bf16 ae[8], int src} ----------------
__global__ __launch_bounds__(256) void k_edge_scatter(const int* __restrict__ ei,
                                                      const float* __restrict__ ea,
                                                      const float* __restrict__ W_edge,
                                                      const float* __restrict__ att_edge,
                                                      const int* __restrict__ rowptr,
                                                      const int* __restrict__ rank,
                                                      unsigned short* __restrict__ recs, int E) {
  __shared__ float Ms[FE * H];
  int t = threadIdx.x;
  if (t < FE * H) {          // M[f][h] = sum_c W_edge[(h*C+c)*FE+f] * att_edge[h*C+c]
    int f = t >> 3, h = t & 7;
    float acc = 0.f;
#pragma unroll
    for (int c = 0; c < C; ++c)
      acc += W_edge[(h * C + c) * FE + f] * att_edge[h * C + c];
    Ms[f * H + h] = acc;
  }
  __syncthreads();
  int e = blockIdx.x * 256 + t;
  if (e >= E) return;
  int s = ei[e], d = ei[E + e];
  const float4* p = (const float4*)&ea[(size_t)e * FE];
  float4 v0 = p[0], v1 = p[1], v2 = p[2], v3 = p[3];
  float eav[FE] = {v0.x, v0.y, v0.z, v0.w, v1.x, v1.y, v1.z, v1.w,
                   v2.x, v2.y, v2.z, v2.w, v3.x, v3.y, v3.z, v3.w};
  float o[H];
#pragma unroll
  for (int h = 0; h < H; ++h) {
    float acc = 0.f;
#pragma unroll
    for (int f = 0; f < FE; ++f) acc += eav[f] * Ms[f * H + h];
    o[h] = acc;
  }
  int pos = rowptr[d] + rank[e];
  uint4 pk;
  pk.x = (unsigned int)f2bf(o[0]) | ((unsigned int)f2bf(o[1]) << 16);
  pk.y = (unsigned int)f2bf(o[2]) | ((unsigned int)f2bf(o[3]) << 16);
  pk.z = (unsigned int)f2bf(o[4]) | ((unsigned int)f2bf(o[5]) << 16);
  pk.w = (unsigned int)f2bf(o[6]) | ((unsigned int)f2bf(o[7]) << 16);
  uint4 hv; hv.x = (unsigned int)s; hv.y = 0; hv.z = 0; hv.w = 0;
  unsigned short* rp = &recs[(size_t)pos * 16];
  *(uint4*)rp = pk;
  *(uint4*)(rp + 8) = hv;
}

// ---------------- wave-per-node: 3-phase softmax + gather, no redundancy, no rescale ----------------
__global__ __launch_bounds__(256) void k_node(const unsigned short* __restrict__ xhb,
                                              const float* __restrict__ a_src,
                                              const float* __restrict__ a_dst,
                                              const unsigned short* __restrict__ recs,
                                              const int* __restrict__ rowptr,
                                              const float* __restrict__ bias,
                                              float* __restrict__ out, int N) {
  __shared__ float wlds[4][512];   // [wave][j*8+h], j<64
  __shared__ int   slds[4][64];
  int wv = threadIdx.x >> 6;
  int lane = threadIdx.x & 63;
  int n = blockIdx.x * 4 + wv;
  if (n >= N) return;
  int start = rowptr[n];
  int deg = rowptr[n + 1] - start;
  int h = lane & 7, esub = lane >> 3;
  float adst = a_dst[n * H + h];
  float asrc = a_src[n * H + h];

  // ---- phase 1: alphas (each (edge,head) once), per-lane max + raw-ae sum ----
  float pmax = -1e30f, psum = 0.f;
  float a0, a1, a2, a3, a4, a5, a6, a7;
#define PH1(IT, AV)                                                          \
  {                                                                          \
    int j = IT * 8 + esub;                                                   \
    float al = -1e30f;                                                       \
    if (j < deg) {                                                           \
      int b = (start + j) * 16;                                              \
      float ae = bf2f(recs[b + h]);                                          \
      int src = *(const int*)&recs[b + 8];                                   \
      if (h == 0) slds[wv][j] = src;                                         \
      psum += ae;                                                            \
      al = a_src[src * H + h] + adst + ae;                                   \
      al = (al >= 0.f) ? al : NEG_SLOPE * al;                                \
      pmax = fmaxf(pmax, al);                                                \
    }                                                                        \
    AV = al;                                                                 \
  }
  PH1(0, a0) PH1(1, a1) PH1(2, a2) PH1(3, a3)
  PH1(4, a4) PH1(5, a5) PH1(6, a6) PH1(7, a7)
#undef PH1
  for (int j0 = 64; j0 < deg; j0 += 8) {   // overflow (deg>64): ~never
    int j = j0 + esub;
    if (j < deg) {
      int b = (start + j) * 16;
      float ae = bf2f(recs[b + h]);
      int src = *(const int*)&recs[b + 8];
      psum += ae;
      float al = a_src[src * H + h] + adst + ae;
      al = (al >= 0.f) ? al : NEG_SLOPE * al;
      pmax = fmaxf(pmax, al);
    }
  }
#pragma unroll
  for (int m = 8; m <= 32; m <<= 1) {
    pmax = fmaxf(pmax, __shfl_xor(pmax, m, 64));
    psum += __shfl_xor(psum, m, 64);
  }
  float aself = asrc + adst + psum / fmaxf((float)deg, 1.f);
  aself = (aself >= 0.f) ? aself : NEG_SLOPE * aself;
  float amax = fmaxf(pmax, aself);

  // ---- phase 2: unnormalized weights -> LDS, per-head denom ----
  float den = 0.f;
#define PH2(IT, AV)                                                          \
  {                                                                          \
    int j = IT * 8 + esub;                                                   \
    if (j < deg) {                                                           \
      float wj = __expf(AV - amax);                                          \
      den += wj;                                                             \
      wlds[wv][j * 8 + h] = wj;                                              \
    }                                                                        \
  }
  PH2(0, a0) PH2(1, a1) PH2(2, a2) PH2(3, a3)
  PH2(4, a4) PH2(5, a5) PH2(6, a6) PH2(7, a7)
#undef PH2
  for (int j0 = 64; j0 < deg; j0 += 8) {
    int j = j0 + esub;
    if (j < deg) {
      int b = (start + j) * 16;
      float ae = bf2f(recs[b + h]);
      int src = *(const int*)&recs[b + 8];
      float al = a_src[src * H + h] + adst + ae;
      al = (al >= 0.f) ? al : NEG_SLOPE * al;
      den += __expf(al - amax);
    }
  }
#pragma unroll
  for (int m = 8; m <= 32; m <<= 1) den += __shfl_xor(den, m, 64);
  float wself = __expf(aself - amax);
  float inv = 1.f / (den + wself);

  // ---- phase 3: gather; lane -> channels lane*4..+3, head hc ----
  int hc = lane >> 3;
  float inv_c  = __shfl(inv, hc, 64);
  float ws_c   = __shfl(wself, hc, 64);
  float amax_c = __shfl(amax, hc, 64);
  float adst_c = __shfl(adst, hc, 64);
  float accx, accy, accz, accw;
  {
    const uint2* px = (const uint2*)(xhb + (((unsigned)n) << 8));
    uint2 u = px[lane];
    accx = ws_c * __uint_as_float(u.x << 16);
    accy = ws_c * __uint_as_float(u.x & 0xffff0000u);
    accz = ws_c * __uint_as_float(u.y << 16);
    accw = ws_c * __uint_as_float(u.y & 0xffff0000u);
  }
  int dlim = (deg < 64) ? deg : 64;
#pragma unroll 2
  for (int j = 0; j < dlim; ++j) {
    float wj = wlds[wv][j * 8 + hc];
    int src = slds[wv][j];
    const uint2* p = (const uint2*)(xhb + (((unsigned)src) << 8));
    uint2 v = p[lane];
    accx = fmaf(__uint_as_float(v.x << 16), wj, accx);
    accy = fmaf(__uint_as_float(v.x & 0xffff0000u), wj, accy);
    accz = fmaf(__uint_as_float(v.y << 16), wj, accz);
    accw = fmaf(__uint_as_float(v.y & 0xffff0000u), wj, accw);
  }
  for (int j = 64; j < deg; ++j) {       // overflow: recompute weight
    int b = (start + j) * 16;
    float ae = bf2f(recs[b + hc]);
    int src = *(const int*)&recs[b + 8];
    float al = a_src[src * H + hc] + adst_c + ae;
    al = (al >= 0.f) ? al : NEG_SLOPE * al;
    float wj = __expf(al - amax_c);
    const uint2* p = (const uint2*)(xhb + (((unsigned)src) << 8));
    uint2 v = p[lane];
    accx = fmaf(__uint_as_float(v.x << 16), wj, accx);
    accy = fmaf(__uint_as_float(v.x & 0xffff0000u), wj, accy);
    accz = fmaf(__uint_as_float(v.y << 16), wj, accz);
    accw = fmaf(__uint_as_float(v.y & 0xffff0000u), wj, accw);
  }
  accx *= inv_c; accy *= inv_c; accz *= inv_c; accw *= inv_c;

  // head mean across hc (xor 8,16,32)
#pragma unroll
  for (int m = 8; m <= 32; m <<= 1) {
    accx += __shfl_xor(accx, m, 64);
    accy += __shfl_xor(accy, m, 64);
    accz += __shfl_xor(accz, m, 64);
    accw += __shfl_xor(accw, m, 64);
  }
  if (lane < 8) {
    float4 b = ((const float4*)bias)[lane];
    float4 o;
    o.x = accx * 0.125f + b.x;
    o.y = accy * 0.125f + b.y;
    o.z = accz * 0.125f + b.z;
    o.w = accw * 0.125f + b.w;
    ((float4*)&out[(size_t)n * C])[lane] = o;
  }
}

extern "C" void kernel_launch(void* const* d_in, const int* in_sizes, int n_in,
                              void* d_out, int out_size, void* d_ws, size_t ws_size,
                              hipStream_t stream) {
  const float* x        = (const float*)d_in[0];
  const int*   ei       = (const int*)d_in[1];
  const float* ea       = (const float*)d_in[2];
  const float* W        = (const float*)d_in[3];
  const float* W_edge   = (const float*)d_in[4];
  const float* att_src  = (const float*)d_in[5];
  const float* att_dst  = (const float*)d_in[6];
  const float* att_edge = (const float*)d_in[7];
  const float* bias     = (const float*)d_in[8];
  float* out = (float*)d_out;

  int N = in_sizes[0] / FIN;
  int E = in_sizes[1] / 2;
  int nb = (N + 255) / 256;

  char* ws = (char*)d_ws;
  auto take = [&](size_t bytes) {
    char* p = ws;
    ws += (bytes + 255) & ~(size_t)255;
    return p;
  };
  unsigned short* xhb    = (unsigned short*)take((size_t)N * HC * 2);
  float*          a_src  = (float*)take((size_t)N * H * 4);
  float*          a_dst  = (float*)take((size_t)N * H * 4);
  unsigned short* recs   = (unsigned short*)take((size_t)E * 32);
  unsigned short* Whi    = (unsigned short*)take((size_t)HC * FIN * 2);
  unsigned short* Wlo    = (unsigned short*)take((size_t)HC * FIN * 2);
  int*            deg    = (int*)take((size_t)N * 4);
  int*            rowptr = (int*)take((size_t)(N + 1) * 4);
  int*            rank   = (int*)take((size_t)E * 4);
  int*            bsum   = (int*)take((size_t)nb * 4);
  int*            boff   = (int*)take((size_t)nb * 4);

  hipMemsetAsync(deg, 0, (size_t)N * 4, stream);
  k_wsplit2<<<(HC * FIN) / 256, 256, 0, stream>>>(W, Whi, Wlo);
  k_deg<<<(E + 255) / 256, 256, 0, stream>>>(ei, deg, rank, E);
  k_xh<<<dim3((N + 127) / 128, 2), 256, 0, stream>>>(x, Whi, Wlo, att_src, att_dst, xhb, a_src, a_dst, N);
  k_scan1<<<nb, 256, 0, stream>>>(deg, bsum, N);
  k_scan2<<<1, 256, 0, stream>>>(bsum, boff, nb);
  k_scan3<<<nb, 256, 0, stream>>>(deg, boff, rowptr, N, E);
  k_edge_scatter<<<(E + 255) / 256, 256, 0, stream>>>(ei, ea, W_edge, att_edge, rowptr, rank, recs, E);
  k_node<<<(N + 3) / 4, 256, 0, stream>>>(xhb, a_src, a_dst, recs, rowptr, bias, out, N);
}